// Round 13
// baseline (254.880 us; speedup 1.0000x reference)
//
#include <hip/hip_runtime.h>

typedef __bf16 bf16x8 __attribute__((ext_vector_type(8)));
typedef float f32x4 __attribute__((ext_vector_type(4)));

#define MFMA(a,b,c) __builtin_amdgcn_mfma_f32_16x16x32_bf16((a),(b),(c),0,0,0)

__device__ __forceinline__ float rcp_(float x){ return __builtin_amdgcn_rcpf(x); }

#define L2E 1.4426950408889634f

// ---------------- prep: fold weights, build per-tid B-frag table -------------
// Per main-kernel tid (0..511): 14 bf16x8 frags (224 B) + 4 f32 (16 B) = 240 B.
//  f0,f1 : G1 T0 (cols = gates i/f x 8 hid)  G1 = L2E*(Whh @ Wh_p)
//  f2,f3 : G1 T1 (cols = gates g/o; g x2)
//  f4,f5 : G2 T0                             G2 = L2E*(Whh @ Wh_u)
//  f6,f7 : G2 T1
//  f8..11: c-tile (cols = Wh2 row hcol, duplicated across l16>>3), K=128 [p|u]
//  f12,13: fc diff (Wfc[0]-Wfc[1] broadcast over cols), K=64
//  scalars: baseT0,dvecT0,baseT1,dvecT1 (pre-scaled by L2E, g-gate x2)
__global__ __launch_bounds__(256) void prep_kernel(
    const float* __restrict__ Wh,  const float* __restrict__ Wh2,
    const float* __restrict__ Whh, const float* __restrict__ Wfc,
    const float* __restrict__ Wih, const float* __restrict__ bih,
    const float* __restrict__ bhh,
    char* __restrict__ tblc)
{
  const int idx = blockIdx.x*256 + threadIdx.x;
  if (idx < 512*14*8){
    const int e = idx & 7, f = (idx >> 3) % 14, t = (idx >> 3) / 14;
    const int w = t >> 6, lane = t & 63, l16 = lane & 15;
    const int g8 = ((lane >> 4) & 3) * 8;
    const int hcol = w*8 + (l16 & 7), hi = l16 >> 3;
    float val;
    if (f < 8){
      const int half = (f >> 2) & 1;          // 0: Wh_p, 1: Wh_u
      const int tile = (f >> 1) & 1;          // 0: T0(i/f), 1: T1(g/o)
      const int s    = f & 1;
      const int gate = tile*2 + hi;
      const int n = gate*64 + hcol;
      const int k = s*32 + g8 + e;
      float acc = 0.f;
      for (int j=0; j<64; ++j) acc += Whh[n*64 + j] * Wh[j*128 + half*64 + k];
      val = acc * ((gate == 2) ? 2.f*L2E : L2E);
    } else if (f < 12){
      const int s = f - 8;
      const int k = (s & 1)*32 + g8 + e;
      val = Wh2[hcol*128 + (s >> 1)*64 + k];
    } else {
      const int k = (f & 1)*32 + g8 + e;
      val = Wfc[k] - Wfc[64 + k];
    }
    *(__bf16*)(tblc + t*240 + f*16 + e*2) = (__bf16)val;
  } else if (idx < 512*14*8 + 512*4){
    const int j = idx - 512*14*8;
    const int t = j >> 2, q = j & 3;
    const int w = t >> 6, lane = t & 63, l16 = lane & 15, hi = l16 >> 3;
    const int tile = q >> 1, kind = q & 1;
    const int gate = tile*2 + hi;
    const int n = gate*64 + w*8 + (l16 & 7);
    const float sc = (gate == 2) ? 2.f*L2E : L2E;
    const float v = kind ? sc*(Wih[n*2] - Wih[n*2+1])
                         : sc*(bih[n] + bhh[n] + Wih[n*2+1]);
    *(float*)(tblc + t*240 + 224 + q*4) = v;
  }
}

// ---------------- main: 256 blocks x 512 threads (8 waves, 16 samples) ------
// Hidden split 8 ways: wave w owns cols [8w,8w+8) of all 4 gates (2 permuted
// N-tiles: T0={i,f}, T1={g,o}) + its c_inter slice (duplicated-col tile).
// 2 waves/SIMD (1 block/CU): per-wave issue ~halves vs R12 (MFMAs 20->12,
// init FMAs 16->8, epilogue 4->2 els/lane) so the two resident waves fill
// each other's stalls at unchanged chip-wide VALU. Carried from R12: rotating
// fc wave ((t-1)&7) + deferred softmax, log2e prescale, merged-rcp epilogue,
// loads-up-front schedule, unroll 4. Gate exchange: 4x shfl_xor(8)/cell.
__global__ __launch_bounds__(512,1) void lstm2d_kernel(
    const float* __restrict__ x,   const float* __restrict__ Wx,
    const float* __restrict__ bfc,
    const char* __restrict__ tblc,
    float* __restrict__ out)
{
  __shared__ __align__(16) __bf16 s_h[16*16*64];   // [col][row][hid] 32 KB
  __shared__ __align__(16) __bf16 s_c[16*16*64];   // 32 KB
  __shared__ __align__(16) float  s_xh[256*16];    // [slot][row] 16 KB
  __shared__ __align__(16) float  s_d[256*16];     // [slot][row] 16 KB
  __shared__ unsigned int s_msk[16*8];             // [row][word] 512 B
  __shared__ float s_red[512];                     // [grp32][row16] 2 KB

  const int tid  = threadIdx.x;
  const int w    = tid >> 6;          // wave 0..7
  const int lane = tid & 63;
  const int l16  = lane & 15;
  const int g4   = lane >> 4;
  const int g8   = g4 * 8;
  const int hi   = l16 >> 3;          // 0: holds i/g cols, 1: holds f/o cols
  const bool lo  = (hi == 0);

  const float wx0 = Wx[0], wx1 = Wx[1];
  const float bd  = bfc[0] - bfc[1];

  // zero h/c
  unsigned int* zh = (unsigned int*)s_h;
  unsigned int* zc = (unsigned int*)s_c;
  #pragma unroll
  for (int it=0; it<16; ++it){ zh[tid + it*512] = 0u; zc[tid + it*512] = 0u; }

  // xh precompute (4096 entries)
  const float* xg = x + blockIdx.x * 4096;
  #pragma unroll
  for (int k=0; k<8; ++k){
    const int idx = tid + k*512;
    const int row = idx & 15, slot = idx >> 4;
    const int i = slot >> 4, t = slot & 15;
    const int c   = (i & 1) ? 15 - t : t;
    const int cpc = (i & 1) ? c + 1 : c - 1;
    const float xp = (t > 0) ? xg[row*256 + i*16 + cpc] : 0.f;
    const float xu = (i > 0) ? xg[row*256 + (i-1)*16 + c] : 0.f;
    s_xh[slot*16 + row] = (xp*wx0 + xu*wx1 + 1.f) * 0.5f;
  }
  // mask bits
  if (tid < 128){
    const int row = tid >> 3, wd = tid & 7;
    unsigned int m = 0;
    for (int b=0; b<32; ++b){
      const int slot = wd*32 + b, i = slot >> 4, t = slot & 15;
      const int c = (i & 1) ? 15 - t : t;
      if (xg[row*256 + i*16 + c] > 0.f) m |= (1u << b);
    }
    s_msk[row*8 + wd] = m;
  }

  // weight fragments
  const char* tb = tblc + tid*240;
  bf16x8 g1T0[2], g1T1[2], g2T0[2], g2T1[2], cB[4], fcB[2];
  g1T0[0] = *(const bf16x8*)(tb +   0); g1T0[1] = *(const bf16x8*)(tb +  16);
  g1T1[0] = *(const bf16x8*)(tb +  32); g1T1[1] = *(const bf16x8*)(tb +  48);
  g2T0[0] = *(const bf16x8*)(tb +  64); g2T0[1] = *(const bf16x8*)(tb +  80);
  g2T1[0] = *(const bf16x8*)(tb +  96); g2T1[1] = *(const bf16x8*)(tb + 112);
  #pragma unroll
  for (int s=0; s<4; ++s) cB[s] = *(const bf16x8*)(tb + 128 + s*16);
  fcB[0] = *(const bf16x8*)(tb + 192); fcB[1] = *(const bf16x8*)(tb + 208);
  const float base0 = *(const float*)(tb + 224);
  const float dvec0 = *(const float*)(tb + 228);
  const float base1 = *(const float*)(tb + 232);
  const float dvec1 = *(const float*)(tb + 236);

  // per-lane LDS offsets (elements); col stride = 1024 els
  const int offA0 = l16*64 + ((     g8) ^ ((l16 & 7) << 3));
  const int offA1 = l16*64 + ((32 + g8) ^ ((l16 & 7) << 3));
  const int habs = w*8 + (l16 & 7);
  int stWa[2];
  #pragma unroll
  for (int e=0; e<2; ++e){
    const int R = g4*4 + 2*hi + e;
    stWa[e] = R*64 + (habs ^ ((R & 7) << 3));
  }
  const int xhOff = g4*4;
  const float C2 = -2.f*L2E;

  __syncthreads();

  f32x4 aT0u, aT1u, aCu;

  for (int i=0; i<16; ++i){
    const int dir = i & 1;
    const int slot0 = i*16;

    // ---- prologue: up contributions for t=0 (+ wave7: d(slot0-1)) ----
    {
      const int bu = (dir ? 15 : 0) << 10;
      bf16x8 h0 = *(const bf16x8*)(s_h + bu + offA0);
      bf16x8 h1 = *(const bf16x8*)(s_h + bu + offA1);
      bf16x8 c0 = *(const bf16x8*)(s_c + bu + offA0);
      bf16x8 c1 = *(const bf16x8*)(s_c + bu + offA1);
      const float4 xh4 = *(const float4*)(s_xh + slot0*16 + xhOff);
      #pragma unroll
      for (int r=0;r<4;++r){
        const float xh = (&xh4.x)[r];
        aT0u[r] = base0 + xh*dvec0;
        aT1u[r] = base1 + xh*dvec1;
      }
      aT0u = MFMA(h0, g2T0[0], aT0u); aT0u = MFMA(h1, g2T0[1], aT0u);
      aT1u = MFMA(h0, g2T1[0], aT1u); aT1u = MFMA(h1, g2T1[1], aT1u);
      f32x4 z = {0.f,0.f,0.f,0.f};
      aCu = MFMA(c0, cB[2], z); aCu = MFMA(c1, cB[3], aCu);
      if (i > 0 && w == 7){                // ((slot0-1)&7) == 7
        f32x4 fz = {bd,bd,bd,bd};
        fz = MFMA(h0, fcB[0], fz);
        f32x4 aF = MFMA(h1, fcB[1], fz);
        if (l16 == 0){
          #pragma unroll
          for (int r=0;r<4;++r) s_d[(slot0-1)*16 + g4*4 + r] = aF[r];
        }
      }
    }

    #pragma unroll 4
    for (int t=0; t<16; ++t){
      const int c    = dir ? 15 - t : t;
      const int slot = slot0 + t;
      const int cb   = c << 10;

      // ---- 1. issue ALL loads up-front ----
      bf16x8 a0, a1, q0, q1;               // prev state (column c(t-1))
      if (t > 0){
        const int b = (dir ? c + 1 : c - 1) << 10;
        a0 = *(const bf16x8*)(s_h + b + offA0);
        a1 = *(const bf16x8*)(s_h + b + offA1);
        q0 = *(const bf16x8*)(s_c + b + offA0);
        q1 = *(const bf16x8*)(s_c + b + offA1);
      }
      bf16x8 au0, au1, cu0, cu1;           // up state for slot+1 (column c(t+1))
      float4 xh4n;
      if (t < 15){
        const int bu = (dir ? 14 - t : t + 1) << 10;
        au0 = *(const bf16x8*)(s_h + bu + offA0);
        au1 = *(const bf16x8*)(s_h + bu + offA1);
        cu0 = *(const bf16x8*)(s_c + bu + offA0);
        cu1 = *(const bf16x8*)(s_c + bu + offA1);
        xh4n = *(const float4*)(s_xh + (slot+1)*16 + xhOff);
      }

      // ---- 2. phase 1: gates + c_inter (+ rotating wave: d(slot-1)) ----
      f32x4 aT0, aT1, aC;
      if (t > 0){
        aT0 = MFMA(a0, g1T0[0], aT0u); aT0 = MFMA(a1, g1T0[1], aT0);
        aT1 = MFMA(a0, g1T1[0], aT1u); aT1 = MFMA(a1, g1T1[1], aT1);
        aC  = MFMA(q0, cB[0], aCu);    aC  = MFMA(q1, cB[1], aC);
        if (w == ((t - 1) & 7)){
          f32x4 fz = {bd,bd,bd,bd};
          fz = MFMA(a0, fcB[0], fz);
          f32x4 aF = MFMA(a1, fcB[1], fz);
          if (l16 == 0){
            #pragma unroll
            for (int r=0;r<4;++r) s_d[(slot-1)*16 + g4*4 + r] = aF[r];
          }
        }
      } else {
        aT0 = aT0u; aT1 = aT1u; aC = aCu;
      }

      // ---- 3. epilogue: gate exchange + merged-rcp activations (2 els) ----
      #pragma unroll
      for (int e=0; e<2; ++e){
        const float sendT0 = lo ? aT0[2+e] : aT0[e];
        const float sendT1 = lo ? aT1[2+e] : aT1[e];
        const float rT0 = __shfl_xor(sendT0, 8);
        const float rT1 = __shfl_xor(sendT1, 8);
        const float own0 = lo ? aT0[e] : aT0[2+e];
        const float own1 = lo ? aT1[e] : aT1[2+e];
        const float ig = lo ? own0 : rT0;
        const float fg = lo ? rT0  : own0;
        const float gg = lo ? own1 : rT1;
        const float og = lo ? rT1  : own1;
        const float cI = lo ? aC[e] : aC[2+e];
        const float A = exp2f(-ig);
        const float F = exp2f(-fg);
        const float B = exp2f(-gg);
        const float O = exp2f(-og);
        const float a1_ = 1.f + A, f1 = 1.f + F, b1 = 1.f + B, o1 = 1.f + O;
        const float pab = a1_ * b1;
        const float num = fmaf(1.f - B, f1, cI * pab);
        const float cn  = num * rcp_(pab * f1);
        const float E   = exp2f(C2 * cn);
        const float hn  = (1.f - E) * rcp_(o1 * (1.f + E));
        s_h[cb + stWa[e]] = (__bf16)hn;
        s_c[cb + stWa[e]] = (__bf16)cn;
      }

      // ---- 4. prefetch MFMAs for slot+1 (reads landed long ago) ----
      if (t < 15){
        #pragma unroll
        for (int r=0;r<4;++r){
          const float xh = (&xh4n.x)[r];
          aT0u[r] = base0 + xh*dvec0;
          aT1u[r] = base1 + xh*dvec1;
        }
        aT0u = MFMA(au0, g2T0[0], aT0u); aT0u = MFMA(au1, g2T0[1], aT0u);
        aT1u = MFMA(au0, g2T1[0], aT1u); aT1u = MFMA(au1, g2T1[1], aT1u);
        f32x4 z = {0.f,0.f,0.f,0.f};
        aCu = MFMA(cu0, cB[2], z); aCu = MFMA(cu1, cB[3], aCu);
      }

      __syncthreads();
    }
  }

  // d(255): slot 255 ends at column 0
  if (w == 7){
    bf16x8 a0 = *(const bf16x8*)(s_h + offA0);
    bf16x8 a1 = *(const bf16x8*)(s_h + offA1);
    f32x4 fz = {bd,bd,bd,bd};
    fz = MFMA(a0, fcB[0], fz);
    f32x4 aF = MFMA(a1, fcB[1], fz);
    if (l16 == 0){
      #pragma unroll
      for (int r=0;r<4;++r) s_d[255*16 + g4*4 + r] = aF[r];
    }
  }
  __syncthreads();

  // ---------- end phase: all 4096 log-softmax terms in parallel ----------
  {
    const int row = tid & 15, grp = tid >> 4;   // 32 groups x 8 slots
    float lpp = 0.f;
    #pragma unroll
    for (int e=0; e<8; ++e){
      const int slot = grp*8 + e;
      const float d = s_d[slot*16 + row];
      const int msk = (s_msk[row*8 + (slot >> 5)] >> (slot & 31)) & 1;
      const float zz = msk ? -d : d;
      lpp -= __logf(1.f + __expf(zz));
    }
    s_red[grp*16 + row] = lpp;
  }
  __syncthreads();
  if (tid < 16){
    const int row = tid;
    float lp = 0.f;
    #pragma unroll
    for (int g=0; g<32; ++g) lp += s_red[g*16 + row];
    int aa = 0;
    #pragma unroll
    for (int wd=0; wd<8; ++wd) aa += __popc(s_msk[row*8 + wd]);
    const int m255 = (s_msk[row*8 + 7] >> 31) & 1;
    if (aa == 1 && m255){
      const float d = s_d[255*16 + row];
      lp += __logf(1.f + __expf(-d));   // remove contrib (factor = 1 - mask)
    }
    out[blockIdx.x*16 + row] = lp;
  }
}

extern "C" void kernel_launch(void* const* d_in, const int* in_sizes, int n_in,
                              void* d_out, int out_size, void* d_ws, size_t ws_size,
                              hipStream_t stream) {
  const float* x   = (const float*)d_in[0];
  const float* Wx  = (const float*)d_in[1];
  const float* Wh  = (const float*)d_in[2];
  const float* Wh2 = (const float*)d_in[3];
  const float* Wih = (const float*)d_in[4];
  const float* Whh = (const float*)d_in[5];
  const float* bih = (const float*)d_in[6];
  const float* bhh = (const float*)d_in[7];
  const float* Wfc = (const float*)d_in[8];
  const float* bfc = (const float*)d_in[9];
  float* out = (float*)d_out;
  char* tbl = (char*)d_ws;    // 512*240 = 122880 B

  prep_kernel<<<dim3(232), dim3(256), 0, stream>>>(
      Wh, Wh2, Whh, Wfc, Wih, bih, bhh, tbl);
  lstm2d_kernel<<<dim3(256), dim3(512), 0, stream>>>(x, Wx, bfc, tbl, out);
}

// Round 14
// 236.537 us; speedup vs baseline: 1.0775x; 1.0775x over previous
//
#include <hip/hip_runtime.h>

typedef __bf16 bf16x8 __attribute__((ext_vector_type(8)));
typedef float f32x4 __attribute__((ext_vector_type(4)));

#define MFMA(a,b,c) __builtin_amdgcn_mfma_f32_16x16x32_bf16((a),(b),(c),0,0,0)

__device__ __forceinline__ float rcp_(float x){ return __builtin_amdgcn_rcpf(x); }

#define L2E 1.4426950408889634f

// ---------------- prep: fold Whh@Wh_p / Whh@Wh_u, build bf16 B-frag table ----
// Per main-kernel tid (0..255): 22 frags x 8 bf16 = 176 elements.
//   f 0..7  : G1[g][s] = L2E*(Whh @ Wh_p)[n][k]   (x2 extra for g==2)
//   f 8..15 : G2[g][s] = L2E*(Whh @ Wh_u)[n][k]
//   f 16..19: bc[s]  = Wh2[n][k]  (K=128 = [prev|up], unscaled)
//   f 20..21: fc[s]  = Wfc[0][k] - Wfc[1][k] (broadcast over n, unscaled)
__global__ __launch_bounds__(256) void prep_kernel(
    const float* __restrict__ Wh,  const float* __restrict__ Wh2,
    const float* __restrict__ Whh, const float* __restrict__ Wfc,
    __bf16* __restrict__ tbl)
{
  const int idx = blockIdx.x*256 + threadIdx.x;
  if (idx >= 256*176) return;
  const int e = idx & 7, f = (idx >> 3) % 22, t = idx / 176;
  const int w = t >> 6, lane = t & 63, l16 = lane & 15, g8 = (lane >> 4) * 8;
  float val;
  if (f < 16){
    const int g = (f >> 1) & 3, s = f & 1, half = f >> 3;
    const int n = g*64 + w*16 + l16;
    const int k = s*32 + g8 + e;
    const float* whcol = Wh + half*64 + k;        // Wh[j][half*64+k], stride 128
    float acc = 0.f;
    for (int j=0; j<64; ++j) acc += Whh[n*64 + j] * whcol[j*128];
    val = acc * ((g == 2) ? 2.f*L2E : L2E);
  } else if (f < 20){
    const int s = f - 16;
    const int n = w*16 + l16;
    const int k = s*32 + g8 + e;
    val = Wh2[n*128 + k];
  } else {
    const int s = f - 20;
    const int k = s*32 + g8 + e;
    val = Wfc[k] - Wfc[64 + k];
  }
  tbl[t*176 + f*8 + e] = (__bf16)val;
}

// ---------------- main: 256 blocks x 256 threads (4 waves, 16 samples) ------
// Measured-optimal structure (R12): 1 block/CU, 16 real samples, 4-wave
// hidden split, one barrier/cell. Techniques: (1) deferred softmax (rotating
// wave ((t-1)&3) parks fc logit-diff d in s_d; parallel end phase);
// (2) log2e-prescaled gate weights -> raw v_exp; (3) merged-rcp epilogue
// (2 rcp instead of 5 per element); (4) latency schedule: all 9 loads issue
// immediately after the barrier, trans block runs before the prefetch MFMAs
// so up-read latency hides under phase-1 MFMA + trans issue.
__global__ __launch_bounds__(256,1) void lstm2d_kernel(
    const float* __restrict__ x,   const float* __restrict__ Wx,
    const float* __restrict__ Wih,
    const float* __restrict__ bih, const float* __restrict__ bhh,
    const float* __restrict__ bfc,
    const __bf16* __restrict__ tbl,
    float* __restrict__ out)
{
  __shared__ __align__(16) __bf16 s_h[16*16*64];   // [col][row][hid] 32 KB
  __shared__ __align__(16) __bf16 s_c[16*16*64];   // 32 KB
  __shared__ __align__(16) float  s_xh[256*16];    // [slot][row] 16 KB
  __shared__ __align__(16) float  s_d[256*16];     // [slot][row] 16 KB
  __shared__ unsigned int s_msk[16*8];             // [row][word] 512 B
  __shared__ float s_red[256];                     // [grp][row] 1 KB

  const int tid  = threadIdx.x;
  const int w    = tid >> 6;
  const int lane = tid & 63;
  const int l16  = lane & 15;
  const int g4   = lane >> 4;
  const int g8   = g4 * 8;

  const float wx0 = Wx[0], wx1 = Wx[1];

  // zero state
  unsigned int* zh = (unsigned int*)s_h;
  unsigned int* zc = (unsigned int*)s_c;
  #pragma unroll
  for (int it=0; it<32; ++it){ zh[tid + it*256] = 0u; zc[tid + it*256] = 0u; }

  // xh precompute: 4096 entries
  const float* xg = x + blockIdx.x * 4096;
  #pragma unroll
  for (int k=0; k<16; ++k){
    const int idx = tid + k*256;
    const int row = idx & 15, slot = idx >> 4;
    const int i = slot >> 4, t = slot & 15;
    const int c   = (i & 1) ? 15 - t : t;
    const int cpc = (i & 1) ? c + 1 : c - 1;
    const float xp = (t > 0) ? xg[row*256 + i*16 + cpc] : 0.f;
    const float xu = (i > 0) ? xg[row*256 + (i-1)*16 + c] : 0.f;
    s_xh[slot*16 + row] = (xp*wx0 + xu*wx1 + 1.f) * 0.5f;
  }
  // mask bits: x>0 at each slot's own cell
  if (tid < 128){
    const int row = tid >> 3, wd = tid & 7;
    unsigned int m = 0;
    for (int b=0; b<32; ++b){
      const int slot = wd*32 + b, i = slot >> 4, t = slot & 15;
      const int c = (i & 1) ? 15 - t : t;
      if (xg[row*256 + i*16 + c] > 0.f) m |= (1u << b);
    }
    s_msk[row*8 + wd] = m;
  }

  // weight fragments from prep table (identical addresses across blocks -> L2)
  const __bf16* tb = tbl + tid*176;
  bf16x8 G1f[4][2], G2f[4][2], bcf[4], fcB[2];
  #pragma unroll
  for (int g=0; g<4; ++g)
    #pragma unroll
    for (int s=0; s<2; ++s){
      G1f[g][s] = *(const bf16x8*)(tb + (g*2+s)*8);
      G2f[g][s] = *(const bf16x8*)(tb + 64 + (g*2+s)*8);
    }
  #pragma unroll
  for (int s=0; s<4; ++s) bcf[s] = *(const bf16x8*)(tb + 128 + s*8);
  #pragma unroll
  for (int s=0; s<2; ++s) fcB[s] = *(const bf16x8*)(tb + 160 + s*8);

  const float bd = bfc[0] - bfc[1];
  float base_[4], dvec_[4];
  #pragma unroll
  for (int g=0; g<4; ++g){
    const int cg = g*64 + w*16 + l16;
    const float sc = (g == 2) ? 2.f*L2E : L2E;
    base_[g] = (bih[cg] + bhh[cg] + Wih[cg*2+1]) * sc;
    dvec_[g] = (Wih[cg*2+0] - Wih[cg*2+1]) * sc;
  }
  const int colw = w*16 + l16;

  // per-lane LDS offsets (elements); col stride = 1024 els
  const int offA0 = l16*64 + ((     g8) ^ ((l16 & 7) << 3));
  const int offA1 = l16*64 + ((32 + g8) ^ ((l16 & 7) << 3));
  int stW[4];
  #pragma unroll
  for (int r=0;r<4;++r){
    const int row = g4*4 + r;
    stW[r] = row*64 + (colw ^ ((row & 7) << 3));
  }
  const float C2 = -2.f*L2E;

  __syncthreads();

  f32x4 accGu[4], aCu;

  for (int i=0; i<16; ++i){
    const int dir = i & 1;
    const int slot0 = i*16;

    // ---- row prologue: up-contribution for t=0 (+ wave3: d(slot0-1)) ----
    {
      const int b = (dir ? 15 : 0) << 10;
      bf16x8 ah0 = *(const bf16x8*)(s_h + b + offA0);
      bf16x8 ah1 = *(const bf16x8*)(s_h + b + offA1);
      bf16x8 qc0 = *(const bf16x8*)(s_c + b + offA0);
      bf16x8 qc1 = *(const bf16x8*)(s_c + b + offA1);
      const float4 xh4 = *(const float4*)(s_xh + slot0*16 + g4*4);
      #pragma unroll
      for (int g=0; g<4; ++g){
        accGu[g][0] = base_[g] + xh4.x * dvec_[g];
        accGu[g][1] = base_[g] + xh4.y * dvec_[g];
        accGu[g][2] = base_[g] + xh4.z * dvec_[g];
        accGu[g][3] = base_[g] + xh4.w * dvec_[g];
        accGu[g] = MFMA(ah0, G2f[g][0], accGu[g]);
        accGu[g] = MFMA(ah1, G2f[g][1], accGu[g]);
      }
      f32x4 z = {0.f,0.f,0.f,0.f};
      aCu = MFMA(qc0, bcf[2], z);
      aCu = MFMA(qc1, bcf[3], aCu);
      if (i > 0 && w == 3){                 // ((slot0-1)&3) == 3
        f32x4 fz = {bd,bd,bd,bd};
        fz = MFMA(ah0, fcB[0], fz);
        f32x4 aF = MFMA(ah1, fcB[1], fz);
        if (l16 == 0){
          #pragma unroll
          for (int r=0;r<4;++r) s_d[(slot0-1)*16 + g4*4 + r] = aF[r];
        }
      }
    }

    #pragma unroll 4
    for (int t=0; t<16; ++t){
      const int c    = dir ? 15 - t : t;
      const int slot = slot0 + t;
      const int cb   = c << 10;

      // ---- 1. issue ALL loads up-front (9 loads in flight) ----
      bf16x8 a0, a1, q0, q1;                // prev state (column c(t-1))
      if (t > 0){
        const int b = (dir ? c + 1 : c - 1) << 10;
        a0 = *(const bf16x8*)(s_h + b + offA0);
        a1 = *(const bf16x8*)(s_h + b + offA1);
        q0 = *(const bf16x8*)(s_c + b + offA0);
        q1 = *(const bf16x8*)(s_c + b + offA1);
      }
      bf16x8 au0, au1, cu0, cu1;            // up state for slot+1 (column c(t+1))
      float4 xh4n;
      if (t < 15){
        const int bu = (dir ? 14 - t : t + 1) << 10;
        au0 = *(const bf16x8*)(s_h + bu + offA0);
        au1 = *(const bf16x8*)(s_h + bu + offA1);
        cu0 = *(const bf16x8*)(s_c + bu + offA0);
        cu1 = *(const bf16x8*)(s_c + bu + offA1);
        xh4n = *(const float4*)(s_xh + (slot+1)*16 + g4*4);
      }

      // ---- 2. phase 1: gates/c_inter for cell t (waits on prev reads only) --
      f32x4 accG[4], aC;
      if (t > 0){
        #pragma unroll
        for (int g=0; g<4; ++g){
          accG[g] = MFMA(a0, G1f[g][0], accGu[g]);
          accG[g] = MFMA(a1, G1f[g][1], accG[g]);
        }
        aC = MFMA(q0, bcf[0], aCu);
        aC = MFMA(q1, bcf[1], aC);
        if (w == ((t - 1) & 3)){
          f32x4 fz = {bd,bd,bd,bd};
          fz = MFMA(a0, fcB[0], fz);
          f32x4 aF = MFMA(a1, fcB[1], fz);
          if (l16 == 0){
            #pragma unroll
            for (int r=0;r<4;++r) s_d[(slot-1)*16 + g4*4 + r] = aF[r];
          }
        }
      } else {
        #pragma unroll
        for (int g=0; g<4; ++g) accG[g] = accGu[g];
        aC = aCu;
      }

      // ---- 3. epilogue trans block (up-read latency hides under this) ----
      // A=2^-i', F=2^-f', B=2^-g'', O=2^-o'
      // cn = [cI*(1+A)(1+B) + (1-B)(1+F)] / [(1+F)(1+A)(1+B)]
      // hn = (1-E)/[(1+O)(1+E)],  E = 2^(-2*l2e*cn)
      float hnv[4], cnv[4];
      #pragma unroll
      for (int r=0;r<4;++r){
        const float A = exp2f(-accG[0][r]);
        const float F = exp2f(-accG[1][r]);
        const float B = exp2f(-accG[2][r]);
        const float O = exp2f(-accG[3][r]);
        const float a1_ = 1.f + A, f1 = 1.f + F, b1 = 1.f + B, o1 = 1.f + O;
        const float pab = a1_ * b1;
        const float num = fmaf(1.f - B, f1, aC[r] * pab);
        const float cn  = num * rcp_(pab * f1);
        const float E   = exp2f(C2 * cn);
        const float hn  = (1.f - E) * rcp_(o1 * (1.f + E));
        hnv[r] = hn; cnv[r] = cn;
      }

      // ---- 4. state writes (issue as soon as values ready) ----
      #pragma unroll
      for (int r=0;r<4;++r){
        s_h[cb + stW[r]] = (__bf16)hnv[r];
        s_c[cb + stW[r]] = (__bf16)cnv[r];
      }

      // ---- 5. prefetch MFMAs for slot+1 (reads landed long ago) ----
      if (t < 15){
        #pragma unroll
        for (int g=0; g<4; ++g){
          accGu[g][0] = base_[g] + xh4n.x * dvec_[g];
          accGu[g][1] = base_[g] + xh4n.y * dvec_[g];
          accGu[g][2] = base_[g] + xh4n.z * dvec_[g];
          accGu[g][3] = base_[g] + xh4n.w * dvec_[g];
          accGu[g] = MFMA(au0, G2f[g][0], accGu[g]);
          accGu[g] = MFMA(au1, G2f[g][1], accGu[g]);
        }
        f32x4 z = {0.f,0.f,0.f,0.f};
        aCu = MFMA(cu0, bcf[2], z);
        aCu = MFMA(cu1, bcf[3], aCu);
      }

      __syncthreads();
    }
  }

  // d(255): slot 255 ends at column 0
  if (w == 3){
    bf16x8 a0 = *(const bf16x8*)(s_h + offA0);
    bf16x8 a1 = *(const bf16x8*)(s_h + offA1);
    f32x4 fz = {bd,bd,bd,bd};
    fz = MFMA(a0, fcB[0], fz);
    f32x4 aF = MFMA(a1, fcB[1], fz);
    if (l16 == 0){
      #pragma unroll
      for (int r=0;r<4;++r) s_d[255*16 + g4*4 + r] = aF[r];
    }
  }
  __syncthreads();

  // ---------- end phase: all 4096 log-softmax terms in parallel ----------
  {
    const int row = tid & 15, grp = tid >> 4;   // 16 groups x 16 slots
    float lpp = 0.f;
    #pragma unroll
    for (int e=0; e<16; ++e){
      const int slot = grp*16 + e;
      const float d = s_d[slot*16 + row];
      const int msk = (s_msk[row*8 + (slot >> 5)] >> (slot & 31)) & 1;
      const float zz = msk ? -d : d;
      lpp -= __logf(1.f + __expf(zz));
    }
    s_red[grp*16 + row] = lpp;
  }
  __syncthreads();
  if (tid < 16){
    const int row = tid;
    float lp = 0.f;
    #pragma unroll
    for (int g=0; g<16; ++g) lp += s_red[g*16 + row];
    int aa = 0;
    #pragma unroll
    for (int wd=0; wd<8; ++wd) aa += __popc(s_msk[row*8 + wd]);
    const int m255 = (s_msk[row*8 + 7] >> 31) & 1;
    if (aa == 1 && m255){
      const float d = s_d[255*16 + row];
      lp += __logf(1.f + __expf(-d));   // remove contrib (factor = 1 - mask)
    }
    out[blockIdx.x*16 + row] = lp;
  }
}

extern "C" void kernel_launch(void* const* d_in, const int* in_sizes, int n_in,
                              void* d_out, int out_size, void* d_ws, size_t ws_size,
                              hipStream_t stream) {
  const float* x   = (const float*)d_in[0];
  const float* Wx  = (const float*)d_in[1];
  const float* Wh  = (const float*)d_in[2];
  const float* Wh2 = (const float*)d_in[3];
  const float* Wih = (const float*)d_in[4];
  const float* Whh = (const float*)d_in[5];
  const float* bih = (const float*)d_in[6];
  const float* bhh = (const float*)d_in[7];
  const float* Wfc = (const float*)d_in[8];
  const float* bfc = (const float*)d_in[9];
  float* out = (float*)d_out;
  __bf16* tbl = (__bf16*)d_ws;   // 256*176*2 = 90112 B

  prep_kernel<<<dim3(176), dim3(256), 0, stream>>>(Wh, Wh2, Whh, Wfc, tbl);
  lstm2d_kernel<<<dim3(256), dim3(256), 0, stream>>>(
      x, Wx, Wih, bih, bhh, bfc, tbl, out);
}